// Round 7
// baseline (113.122 us; speedup 1.0000x reference)
//
#include <hip/hip_runtime.h>

#define NB   2
#define SKV  1024
#define NSQ  512
#define HIN  256
#define HA   128

// projections pre-scaled by 2*log2(e):  exp2(KSC*x) = e^{2x}
// tanh(x) = 1 - 2/(e^{2x}+1); softmax is shift-invariant so the constant
// W0+bv terms of the score are dropped entirely.
#define KSC   2.8853900817779268f   // 2*log2(e)

// ---------------- Kernel A: projections -> exponentials ----------------
// (R2 version, unchanged — best measured build.)
// kv rows -> ekT, INTERLEAVED-TRANSPOSED: ekT[b][a>>2][s][a&3]; q rows -> eq
// row-major [r][a].
__global__ __launch_bounds__(512) void proj_kernel(
    const float* __restrict__ kv,
    const float* __restrict__ qy,
    const float* __restrict__ Wkv,
    const float* __restrict__ bkv,
    const float* __restrict__ Wq,
    const float* __restrict__ bq,
    float* __restrict__ ekT,
    float* __restrict__ eq)
{
    __shared__ __align__(16) float rowf[8][HIN];
    const int t  = threadIdx.x;
    const int a  = t & 127;            // output channel
    const int rh = t >> 7;             // row-pair id (0..3)
    const int r0 = blockIdx.x * 8;     // 8 rows per block
    const bool is_q = (r0 >= NB * SKV);
    const float* __restrict__ src = is_q ? (qy + (size_t)(r0 - NB * SKV) * HIN)
                                         : (kv + (size_t)r0 * HIN);
    const float* __restrict__ W  = is_q ? Wq : Wkv;
    const float* __restrict__ bs = is_q ? bq : bkv;

    ((float4*)rowf)[t] = ((const float4*)src)[t];
    __syncthreads();

    float a0 = 0.f, a1 = 0.f;
    const int ra = rh * 2, rb = rh * 2 + 1;
    #pragma unroll 4
    for (int h4 = 0; h4 < 64; ++h4) {
        const float4 r4a = ((const float4*)rowf[ra])[h4];
        const float4 r4b = ((const float4*)rowf[rb])[h4];
        #pragma unroll
        for (int j = 0; j < 4; ++j) {
            const float w = W[(size_t)(h4 * 4 + j) * HA + a];
            a0 = fmaf(((const float*)&r4a)[j], w, a0);
            a1 = fmaf(((const float*)&r4b)[j], w, a1);
        }
    }
    const float bb = bs[a];
    const float e0 = __builtin_amdgcn_exp2f((a0 + bb) * KSC);
    const float e1 = __builtin_amdgcn_exp2f((a1 + bb) * KSC);
    if (is_q) {
        const int r = r0 - NB * SKV;
        eq[(size_t)(r + ra) * HA + a] = e0;
        eq[(size_t)(r + rb) * HA + a] = e1;
    } else {
        const int bI = r0 >> 10, s0 = r0 & 1023;
        float* __restrict__ p =
            ekT + ((size_t)(bI * 32 + (a >> 2)) * SKV + s0) * 4 + (a & 3);
        p[(size_t)ra * 4] = e0;
        p[(size_t)rb * 4] = e1;
    }
}

// ---------------- Kernel B: scores + softmax + weights + output (FUSED) ----
// one block = 2 (b,q) rows; 512 threads (8 waves); grid 512 => 2 blocks/CU.
// Two co-resident blocks interleave phases: block A's VALU-bound score phase
// overlaps block B's L2-bound output phase; barriers stall only half the CU.
__global__ __launch_bounds__(512) void attn_kernel(
    const float* __restrict__ ekT,         // (b,32,1024,4) interleaved exps
    const float* __restrict__ eq,          // (1024,128) exps, row-major
    const float* __restrict__ wv,          // (128)
    const float* __restrict__ kv,          // (2048,256) f32
    float* __restrict__ out)               // [262144 out0][1048576 weights]
{
    __shared__ __align__(16) float eq_s[2][HA];        // 1 KB
    __shared__ __align__(16) float wv_s[HA];           // 0.5 KB
    __shared__ __align__(16) float wt_s[SKV][2];       // 8 KB
    __shared__ __align__(16) float part[8][2][HIN];    // 16 KB
    __shared__ float red[2][2][8];

    const int tid  = threadIdx.x;
    const int lane = tid & 63, wid = tid >> 6;
    const int bq0  = blockIdx.x * 2;       // never straddles b (512%2==0)
    const int b    = bq0 >> 9;

    if (tid < 256) ((float*)eq_s)[tid] = eq[(size_t)bq0 * HA + tid];
    else if (tid < 384) wv_s[tid - 256] = wv[tid - 256];
    __syncthreads();

    // ---- phase 2: 2 s per thread, 2 q accumulators; paired rcp over a ----
    const float4* __restrict__ E4 = (const float4*)ekT + (size_t)b * 32 * SKV;
    float sc[2][2];                        // [q][si]
    #pragma unroll
    for (int si = 0; si < 2; ++si) {
        const int s = si * 512 + tid;
        float t0 = 0.f, t1 = 0.f;
        #pragma unroll 4
        for (int a4 = 0; a4 < 32; ++a4) {
            const float4 E = E4[(size_t)a4 * SKV + s];     // coalesced b128
            const float4 w = ((const float4*)wv_s)[a4];    // LDS broadcast

#define PQ(ACC, QI)                                                           \
            {                                                                 \
                const float4 Q = ((const float4*)eq_s[QI])[a4];               \
                float u  = fmaf(E.x, Q.x, 1.f);                               \
                float v  = fmaf(E.y, Q.y, 1.f);                               \
                ACC = fmaf(fmaf(w.x, v, w.y * u),                             \
                           __builtin_amdgcn_rcpf(u * v), ACC);                \
                float u2 = fmaf(E.z, Q.z, 1.f);                               \
                float v2 = fmaf(E.w, Q.w, 1.f);                               \
                ACC = fmaf(fmaf(w.z, v2, w.w * u2),                           \
                           __builtin_amdgcn_rcpf(u2 * v2), ACC);              \
            }
            PQ(t0, 0) PQ(t1, 1)
#undef PQ
        }
        sc[0][si] = t0; sc[1][si] = t1;
    }

    // ---- phase 3: softmax over s.  weight ∝ exp(-2*(t - tmin)) ----
    #pragma unroll
    for (int q = 0; q < 2; ++q) {
        float m = fminf(sc[q][0], sc[q][1]);
        #pragma unroll
        for (int o = 32; o > 0; o >>= 1) m = fminf(m, __shfl_down(m, o));
        if (lane == 0) red[0][q][wid] = m;
    }
    __syncthreads();
    float M[2];
    #pragma unroll
    for (int q = 0; q < 2; ++q) {
        float m = red[0][q][0];
        #pragma unroll
        for (int i = 1; i < 8; ++i) m = fminf(m, red[0][q][i]);
        M[q] = m;
    }
    float e[2][2];
    #pragma unroll
    for (int q = 0; q < 2; ++q) {
        e[q][0] = __builtin_amdgcn_exp2f((M[q] - sc[q][0]) * KSC);
        e[q][1] = __builtin_amdgcn_exp2f((M[q] - sc[q][1]) * KSC);
        float sum = e[q][0] + e[q][1];
        #pragma unroll
        for (int o = 32; o > 0; o >>= 1) sum += __shfl_down(sum, o);
        if (lane == 0) red[1][q][wid] = sum;
    }
    __syncthreads();
    float* __restrict__ outw = out + (size_t)NB * NSQ * HIN;   // weights at 262144
    float rd[2];
    #pragma unroll
    for (int q = 0; q < 2; ++q) {
        float d = red[1][q][0];
        #pragma unroll
        for (int i = 1; i < 8; ++i) d += red[1][q][i];
        rd[q] = __builtin_amdgcn_rcpf(d);
    }
    #pragma unroll
    for (int si = 0; si < 2; ++si) {
        const int s = si * 512 + tid;
        const float w0 = e[0][si] * rd[0];
        const float w1 = e[1][si] * rd[1];
        wt_s[s][0] = w0;
        wt_s[s][1] = w1;
        outw[(size_t)(bq0 + 0) * SKV + s] = w0;        // coalesced per q
        outw[(size_t)(bq0 + 1) * SKV + s] = w1;
    }
    __syncthreads();

    // ---- phase 4: out[q][h] = sum_s w[q][s]*kv[b][s][h] ----
    // wave g handles s in [g*128, g*128+128); lane = float4 chunk of h
    {
        const int g = wid;                 // 0..7
        float4 ac0 = {0,0,0,0}, ac1 = {0,0,0,0};
        const float4* __restrict__ kvb =
            (const float4*)kv + (size_t)(b * SKV + g * 128) * 64;
        #pragma unroll 4
        for (int i = 0; i < 128; ++i) {
            const float w0 = wt_s[g * 128 + i][0];            // LDS broadcast
            const float w1 = wt_s[g * 128 + i][1];
            const float4 v = kvb[(size_t)i * 64 + lane];      // coalesced 1KB/wave
            ac0.x = fmaf(w0, v.x, ac0.x); ac0.y = fmaf(w0, v.y, ac0.y);
            ac0.z = fmaf(w0, v.z, ac0.z); ac0.w = fmaf(w0, v.w, ac0.w);
            ac1.x = fmaf(w1, v.x, ac1.x); ac1.y = fmaf(w1, v.y, ac1.y);
            ac1.z = fmaf(w1, v.z, ac1.z); ac1.w = fmaf(w1, v.w, ac1.w);
        }
        ((float4*)part[g][0])[lane] = ac0;
        ((float4*)part[g][1])[lane] = ac1;
    }
    __syncthreads();
    {
        const int q = tid >> 8, h = tid & 255;       // 512 outputs, 1/thread
        float v = 0.f;
        #pragma unroll
        for (int g2 = 0; g2 < 8; ++g2) v += part[g2][q][h];    // stride-1 banks
        out[(size_t)(bq0 + q) * HIN + h] = v;        // coalesced
    }
}

extern "C" void kernel_launch(void* const* d_in, const int* in_sizes, int n_in,
                              void* d_out, int out_size, void* d_ws, size_t ws_size,
                              hipStream_t stream) {
    (void)in_sizes; (void)n_in; (void)out_size; (void)ws_size;
    const float* kv  = (const float*)d_in[0];
    const float* qy  = (const float*)d_in[1];
    const float* Wkv = (const float*)d_in[2];
    const float* bkv = (const float*)d_in[3];
    const float* Wq  = (const float*)d_in[4];
    const float* bq  = (const float*)d_in[5];
    const float* wv  = (const float*)d_in[6];
    float* ekT = (float*)d_ws;                 // 1 MB
    float* eqp = ekT + (size_t)NB * SKV * HA;  // 0.5 MB
    float* out = (float*)d_out;

    hipLaunchKernelGGL(proj_kernel, dim3((NB * SKV + NB * NSQ) / 8), dim3(512), 0, stream,
                       kv, qy, Wkv, bkv, Wq, bq, ekT, eqp);
    hipLaunchKernelGGL(attn_kernel, dim3(NB * NSQ / 2), dim3(512), 0, stream,
                       ekT, eqp, wv, kv, out);
}